// Round 4
// baseline (357.985 us; speedup 1.0000x reference)
//
#include <hip/hip_runtime.h>
#include <hip/hip_bf16.h>
#include <math.h>

// Problem constants: B=8, N=100, D=768, H=768, TH=24, T=577.
#define PB   8
#define PN   100
#define PD   768
#define PT   577
#define PTH  24
#define BN_TOT 800
#define MPAD   832            // 800 padded to 26*32

#define NBLK 416              // grid: 2 blocks/CU co-resident (<= 512)
#define NTHR 256
#define TOTTHR (NBLK * NTHR)  // 106496

typedef __attribute__((ext_vector_type(8))) short bf16x8;   // 8 bf16
typedef __attribute__((ext_vector_type(4))) float f32x4;

// ws layout (bytes):
//   Sx       f32 [8][24][25][768]   = 14,745,600   (x-prefix SAT, col 0 = 0)
//   pooledh  bf16 [832][768]        =  1,277,952
//   W1T      bf16 [1536][768]       =  2,359,296
//   hab      f32 [832][1536]        =  5,111,808
//   bar      unsigned[256]          =  1,024
#define OFF_POOLED 14745600
#define OFF_W1T    16023552
#define OFF_HAB    18382848
#define OFF_BAR    23494656

// ---------------------------------------------------------------------------
// One-shot grid barrier (all NBLK blocks co-resident by construction).
// cnt and flag live on separate cachelines.
// ---------------------------------------------------------------------------
__device__ __forceinline__ void gbar(unsigned* cnt, unsigned* flag) {
    __syncthreads();
    if (threadIdx.x == 0) {
        __threadfence();   // release: make this block's writes device-visible
        unsigned prev = __hip_atomic_fetch_add(cnt, 1u, __ATOMIC_ACQ_REL,
                                               __HIP_MEMORY_SCOPE_AGENT);
        if (prev == NBLK - 1) {
            __hip_atomic_store(flag, 1u, __ATOMIC_RELEASE,
                               __HIP_MEMORY_SCOPE_AGENT);
        } else {
            while (__hip_atomic_load(flag, __ATOMIC_ACQUIRE,
                                     __HIP_MEMORY_SCOPE_AGENT) == 0u)
                __builtin_amdgcn_s_sleep(2);
        }
        __threadfence();   // acquire: invalidate caches before reading others
    }
    __syncthreads();
}

__device__ __forceinline__ float rdot(const float4 A, const float4 C,
                                      const float4 W, float s) {
    s = fmaf(fmaxf(A.x + C.x, 0.f), W.x, s);
    s = fmaf(fmaxf(A.y + C.y, 0.f), W.y, s);
    s = fmaf(fmaxf(A.z + C.z, 0.f), W.z, s);
    s = fmaf(fmaxf(A.w + C.w, 0.f), W.w, s);
    return s;
}

// ---------------------------------------------------------------------------
// Fused kernel: P0 satx + W1T cvt | P1 pool | P2 MFMA GEMM | P3 pair.
// ---------------------------------------------------------------------------
__global__ __launch_bounds__(NTHR, 2) void fused_kernel(
    const float* __restrict__ patch,   // [8,577,768]
    const float* __restrict__ boxes,   // [800,4]
    const float* __restrict__ W1,      // [1536,768]
    const float* __restrict__ b1,      // [768]
    const float* __restrict__ W2,      // [768]
    const float* __restrict__ b2,      // [1]
    const int*   __restrict__ img_h,
    const int*   __restrict__ img_w,
    float* __restrict__ out,           // [8,100,100]
    char* __restrict__ wsb)
{
    __shared__ float tile[32][33];

    float*          Sx      = (float*)(wsb);
    __hip_bfloat16* pooledh = (__hip_bfloat16*)(wsb + OFF_POOLED);
    __hip_bfloat16* W1T     = (__hip_bfloat16*)(wsb + OFF_W1T);
    float*          hab     = (float*)(wsb + OFF_HAB);
    unsigned*       bar     = (unsigned*)(wsb + OFF_BAR);

    const int bid = blockIdx.x;
    const int t   = threadIdx.x;

    // ============================ P0 ======================================
    if (bid < 144) {
        // satx: one thread per (b, y, d4).  144*256 = 36864 = 8*24*192.
        const int gid = bid * 256 + t;
        const int d4 = gid % 192;
        const int y  = (gid / 192) % PTH;
        const int b  = gid / (192 * PTH);

        const float4* src = (const float4*)(patch +
                            ((size_t)(b * PT + 1 + y * PTH)) * PD);
        float4* dst = (float4*)(Sx + ((size_t)(b * PTH + y) * 25) * PD) + d4;

        dst[0] = make_float4(0.f, 0.f, 0.f, 0.f);
        float4 acc = make_float4(0.f, 0.f, 0.f, 0.f);
#pragma unroll
        for (int X = 1; X <= PTH; ++X) {
            float4 v = src[(size_t)(X - 1) * 192 + d4];
            acc.x += v.x; acc.y += v.y; acc.z += v.z; acc.w += v.w;
            dst[(size_t)X * 192] = acc;
        }
    } else {
        // cvt W1T[n][k] = W1[k + 768*(n>=768)][n&767]; 1152 32x32 tiles.
        for (int tl = bid - 144; tl < 1152; tl += NBLK - 144) {
            const int hf  = tl / 576;
            const int rem = tl % 576;
            const int k0 = (rem / 24) * 32;
            const int n0 = (rem % 24) * 32;
            const int c  = t & 31;
            const int r4 = t >> 5;
#pragma unroll
            for (int l = 0; l < 4; ++l) {
                int r = r4 + 8 * l;
                tile[r][c] = W1[(size_t)(hf * PD + k0 + r) * PD + n0 + c];
            }
            __syncthreads();
#pragma unroll
            for (int l = 0; l < 4; ++l) {
                int r = r4 + 8 * l;
                W1T[(size_t)(hf * PD + n0 + r) * PD + k0 + c] =
                    __float2bfloat16(tile[c][r]);
            }
            __syncthreads();
        }
    }
    gbar(bar + 0, bar + 32);

    // ============================ P1: pool ================================
    {
        const float Wf = (float)img_w[0];
        const float Hf = (float)img_h[0];
        for (int u = bid * 256 + t; u < MPAD * 192; u += TOTTHR) {
            const int m  = u / 192;
            const int d4 = u % 192;
            short4* o = (short4*)(pooledh + (size_t)m * PD) + d4;
            if (m >= BN_TOT) {
                short4 z; z.x = 0; z.y = 0; z.z = 0; z.w = 0;
                *o = z;
                continue;
            }
            const int b = m / PN;
            auto to_patch = [](float v, float size) -> int {
                float pix = floorf(v * size);
                float tt  = pix / size * (float)PTH;
                return (int)floorf(tt);
            };
            int px1 = min(max(to_patch(boxes[m * 4 + 0], Wf), 0), PTH - 1);
            int py1 = min(max(to_patch(boxes[m * 4 + 1], Hf), 0), PTH - 1);
            int px2 = min(max(to_patch(boxes[m * 4 + 2], Wf), 1), PTH);
            int py2 = min(max(to_patch(boxes[m * 4 + 3], Hf), 1), PTH);
            if (px2 <= px1) px2 = px1 + 1;
            if (py2 <= py1) py2 = py1 + 1;
            const float inv = 1.0f / (float)((px2 - px1) * (py2 - py1));

            const float* Sb = Sx + (size_t)b * PTH * 25 * PD;
            float4 s = make_float4(0.f, 0.f, 0.f, 0.f);
            for (int y = py1; y < py2; ++y) {
                const float4* r2 = (const float4*)(Sb + ((size_t)y * 25 + px2) * PD) + d4;
                const float4* r1 = (const float4*)(Sb + ((size_t)y * 25 + px1) * PD) + d4;
                float4 a2 = *r2, a1 = *r1;
                s.x += a2.x - a1.x; s.y += a2.y - a1.y;
                s.z += a2.z - a1.z; s.w += a2.w - a1.w;
            }
            auto cvt = [](float f) -> short {
                __hip_bfloat16 h = __float2bfloat16(f);
                return *(short*)&h;
            };
            short4 r;
            r.x = cvt(s.x * inv); r.y = cvt(s.y * inv);
            r.z = cvt(s.z * inv); r.w = cvt(s.w * inv);
            *o = r;
        }
    }
    gbar(bar + 64, bar + 96);

    // ============================ P2: GEMM ================================
    // C[832][1536] = pooledh * W1T^T.  312 tiles of 64x64; 4 waves each 32x32.
    if (bid < 312) {
        const int bm = bid / 24;
        const int bn = bid % 24;
        const int wave = t >> 6;
        const int lane = t & 63;
        const int lm = lane & 15;
        const int g  = lane >> 4;
        const int m0 = bm * 64 + (wave >> 1) * 32;
        const int n0 = bn * 64 + (wave & 1) * 32;

        const __hip_bfloat16* pa0 = pooledh + (size_t)(m0 + lm) * PD + g * 8;
        const __hip_bfloat16* pa1 = pa0 + (size_t)16 * PD;
        const __hip_bfloat16* pb0 = W1T + (size_t)(n0 + lm) * PD + g * 8;
        const __hip_bfloat16* pb1 = pb0 + (size_t)16 * PD;

        f32x4 acc00 = {}, acc01 = {}, acc10 = {}, acc11 = {};
#pragma unroll 4
        for (int k0 = 0; k0 < PD; k0 += 32) {
            bf16x8 a0 = *(const bf16x8*)(pa0 + k0);
            bf16x8 a1 = *(const bf16x8*)(pa1 + k0);
            bf16x8 b0 = *(const bf16x8*)(pb0 + k0);
            bf16x8 b1v = *(const bf16x8*)(pb1 + k0);
            acc00 = __builtin_amdgcn_mfma_f32_16x16x32_bf16(a0, b0,  acc00, 0, 0, 0);
            acc01 = __builtin_amdgcn_mfma_f32_16x16x32_bf16(a0, b1v, acc01, 0, 0, 0);
            acc10 = __builtin_amdgcn_mfma_f32_16x16x32_bf16(a1, b0,  acc10, 0, 0, 0);
            acc11 = __builtin_amdgcn_mfma_f32_16x16x32_bf16(a1, b1v, acc11, 0, 0, 0);
        }
        // C/D layout: col = lane&15, row = (lane>>4)*4 + reg
        const int rbase = g * 4;
#pragma unroll
        for (int r = 0; r < 4; ++r) {
            int row0 = m0 + rbase + r;
            int row1 = row0 + 16;
            int col0 = n0 + lm;
            int col1 = col0 + 16;
            float bb0 = (col0 < PD) ? b1[col0] : 0.0f;
            float bb1 = (col1 < PD) ? b1[col1] : 0.0f;
            hab[(size_t)row0 * 1536 + col0] = acc00[r] + bb0;
            hab[(size_t)row0 * 1536 + col1] = acc01[r] + bb1;
            hab[(size_t)row1 * 1536 + col0] = acc10[r] + bb0;
            hab[(size_t)row1 * 1536 + col1] = acc11[r] + bb1;
        }
    }
    gbar(bar + 128, bar + 160);

    // ============================ P3: pair ================================
    // unit = bid: jt = bid&3 (25 j's), it = (bid>>2)%13 (8 i rows), b = bid/52.
    {
        const int jt = bid & 3;
        const int it = (bid >> 2) % 13;
        const int b  = bid / 52;
        const int i0 = it * 8;
        const int nrows = min(8, PN - i0);
        const int wave = t >> 6;
        const int lane = t & 63;

        const float4* w2v = (const float4*)W2;
        const float4 w0 = w2v[lane], w1 = w2v[lane + 64], w2r = w2v[lane + 128];
        const float bb2 = b2[0];

        float4 a[8][3];
#pragma unroll
        for (int i = 0; i < 8; ++i) {
            int row = b * PN + (i < nrows ? i0 + i : i0);
            const float4* ha = (const float4*)(hab + (size_t)row * 1536);
            a[i][0] = ha[lane]; a[i][1] = ha[lane + 64]; a[i][2] = ha[lane + 128];
        }

        const float4* hbbase = (const float4*)(hab + (size_t)(b * PN) * 1536) + 192;
        const int jend = jt * 25 + 25;
        int j = jt * 25 + wave;

        float4 h0, h1, h2;
        {
            const float4* hb = hbbase + (size_t)j * 384;
            h0 = hb[lane]; h1 = hb[lane + 64]; h2 = hb[lane + 128];
        }
        for (; j < jend; j += 4) {
            const float4 c0 = h0, c1 = h1, c2 = h2;
            const int jn = j + 4;
            if (jn < jend) {
                const float4* hb = hbbase + (size_t)jn * 384;
                h0 = hb[lane]; h1 = hb[lane + 64]; h2 = hb[lane + 128];
            }
            float acc[8];
#pragma unroll
            for (int i = 0; i < 8; ++i)
                acc[i] = rdot(a[i][2], c2, w2r,
                         rdot(a[i][1], c1, w1,
                         rdot(a[i][0], c0, w0, 0.f)));
#pragma unroll
            for (int i = 0; i < 8; ++i)
#pragma unroll
                for (int m = 32; m; m >>= 1)
                    acc[i] += __shfl_xor(acc[i], m, 64);
            if (lane == 0) {
#pragma unroll
                for (int i = 0; i < 8; ++i)
                    if (i < nrows)
                        out[(size_t)(b * PN + i0 + i) * PN + j] =
                            1.0f / (1.0f + expf(-(acc[i] + bb2)));
            }
        }
    }
}

// ---------------------------------------------------------------------------
extern "C" void kernel_launch(void* const* d_in, const int* in_sizes, int n_in,
                              void* d_out, int out_size, void* d_ws, size_t ws_size,
                              hipStream_t stream) {
    const float* patch = (const float*)d_in[0];
    const float* boxes = (const float*)d_in[1];
    const float* W1    = (const float*)d_in[2];
    const float* b1    = (const float*)d_in[3];
    const float* W2    = (const float*)d_in[4];
    const float* b2    = (const float*)d_in[5];
    const int*   img_h = (const int*)d_in[6];
    const int*   img_w = (const int*)d_in[7];
    float* out = (float*)d_out;
    char* wsb = (char*)d_ws;

    hipMemsetAsync(wsb + OFF_BAR, 0, 1024, stream);
    fused_kernel<<<NBLK, NTHR, 0, stream>>>(patch, boxes, W1, b1, W2, b2,
                                            img_h, img_w, out, wsb);
}

// Round 6
// 206.655 us; speedup vs baseline: 1.7323x; 1.7323x over previous
//
#include <hip/hip_runtime.h>
#include <hip/hip_bf16.h>
#include <math.h>

// Problem constants: B=8, N=100, D=768, H=768, TH=24, T=577.
#define PB   8
#define PN   100
#define PD   768
#define PT   577
#define PTH  24
#define BN_TOT 800
#define MPAD   832            // 800 padded to 26*32

typedef __attribute__((ext_vector_type(8))) short bf16x8;   // 8 bf16
typedef __attribute__((ext_vector_type(4))) float f32x4;

// ---------------------------------------------------------------------------
// Kernel 1: brute-force ROI mean pool (no SAT) + W1T bf16 transpose, fused.
// Block = one pooled row m (832 blocks, 256 thr). Threads 0..191 pool the
// row as float4 over d; then all 256 threads grid-stride the 1152 32x32
// transpose tiles of W1 (independent input -> no ordering hazard).
// ---------------------------------------------------------------------------
__global__ __launch_bounds__(256) void pool_prep_kernel(
    const float* __restrict__ patch,   // [8,577,768]
    const float* __restrict__ boxes,   // [800,4]
    const float* __restrict__ W1,      // [1536,768]
    const int*   __restrict__ img_h,
    const int*   __restrict__ img_w,
    __hip_bfloat16* __restrict__ pooledh,  // [832,768]
    __hip_bfloat16* __restrict__ W1T)      // [1536,768]: W1T[n][k]
{
    __shared__ float tile[32][33];
    const int m = blockIdx.x;          // 0..831
    const int t = threadIdx.x;

    // ---- part A: pooling (threads 0..191, one float4 d-group each) ----
    if (t < 192) {
        short4* o = (short4*)(pooledh + (size_t)m * PD) + t;
        if (m >= BN_TOT) {
            short4 z; z.x = 0; z.y = 0; z.z = 0; z.w = 0;
            *o = z;
        } else {
            const int b = m / PN;
            const float Wf = (float)img_w[0];
            const float Hf = (float)img_h[0];
            auto to_patch = [](float v, float size) -> int {
                float pix = floorf(v * size);
                float tt  = pix / size * (float)PTH;
                return (int)floorf(tt);
            };
            int px1 = min(max(to_patch(boxes[m * 4 + 0], Wf), 0), PTH - 1);
            int py1 = min(max(to_patch(boxes[m * 4 + 1], Hf), 0), PTH - 1);
            int px2 = min(max(to_patch(boxes[m * 4 + 2], Wf), 1), PTH);
            int py2 = min(max(to_patch(boxes[m * 4 + 3], Hf), 1), PTH);
            if (px2 <= px1) px2 = px1 + 1;
            if (py2 <= py1) py2 = py1 + 1;
            const float inv = 1.0f / (float)((px2 - px1) * (py2 - py1));

            const float* pb_ = patch + (size_t)(b * PT + 1) * PD;
            float4 s = make_float4(0.f, 0.f, 0.f, 0.f);
            for (int y = py1; y < py2; ++y) {
                const float* rowp = pb_ + (size_t)(y * PTH) * PD;
                for (int x = px1; x < px2; ++x) {
                    float4 v = ((const float4*)(rowp + (size_t)x * PD))[t];
                    s.x += v.x; s.y += v.y; s.z += v.z; s.w += v.w;
                }
            }
            auto cvt = [](float f) -> short {
                __hip_bfloat16 h = __float2bfloat16(f);
                return *(short*)&h;
            };
            short4 r;
            r.x = cvt(s.x * inv); r.y = cvt(s.y * inv);
            r.z = cvt(s.z * inv); r.w = cvt(s.w * inv);
            *o = r;
        }
    }

    // ---- part B: W1T[n][k] = W1[k + 768*(n>=768)][n&767]; 1152 tiles ----
    // (uniform trip count per block; __syncthreads legal)
    for (int tl = m; tl < 1152; tl += MPAD) {
        const int hf  = tl / 576;
        const int rem = tl % 576;
        const int k0 = (rem / 24) * 32;
        const int n0 = (rem % 24) * 32;
        const int c  = t & 31;
        const int r4 = t >> 5;             // 0..7
        __syncthreads();
#pragma unroll
        for (int l = 0; l < 4; ++l) {
            int r = r4 + 8 * l;
            tile[r][c] = W1[(size_t)(hf * PD + k0 + r) * PD + n0 + c];
        }
        __syncthreads();
#pragma unroll
        for (int l = 0; l < 4; ++l) {
            int r = r4 + 8 * l;            // n-offset within tile
            W1T[(size_t)(hf * PD + n0 + r) * PD + k0 + c] =
                __float2bfloat16(tile[c][r]);
        }
    }
}

// ---------------------------------------------------------------------------
// Kernel 2: bf16 MFMA GEMM.  hab[832][1536] = pooledh * W1T^T  (+b1 on n<768).
// Tile 32(M) x 64(N); 2 waves; fragments direct from global (L2-resident).
// ---------------------------------------------------------------------------
__global__ __launch_bounds__(128) void gemm_mfma_kernel(
    const __hip_bfloat16* __restrict__ A,    // pooled bf16 [832][768]
    const __hip_bfloat16* __restrict__ Bt,   // W1T bf16 [1536][768]
    const float* __restrict__ b1,            // [768]
    float* __restrict__ C)                   // hab [832][1536]
{
    const int bn = blockIdx.x;               // 0..23
    const int bm = blockIdx.y;               // 0..25
    const int wave = threadIdx.x >> 6;       // 0..1
    const int lane = threadIdx.x & 63;
    const int lm = lane & 15;
    const int g  = lane >> 4;                // 0..3

    const int m0 = bm * 32;
    const int n0 = bn * 64 + wave * 32;

    const __hip_bfloat16* pa0 = A  + (size_t)(m0 + lm) * PD + g * 8;
    const __hip_bfloat16* pa1 = pa0 + (size_t)16 * PD;
    const __hip_bfloat16* pb0 = Bt + (size_t)(n0 + lm) * PD + g * 8;
    const __hip_bfloat16* pb1 = pb0 + (size_t)16 * PD;

    f32x4 acc00 = {}, acc01 = {}, acc10 = {}, acc11 = {};

#pragma unroll 4
    for (int k0 = 0; k0 < PD; k0 += 32) {
        bf16x8 a0 = *(const bf16x8*)(pa0 + k0);
        bf16x8 a1 = *(const bf16x8*)(pa1 + k0);
        bf16x8 b0 = *(const bf16x8*)(pb0 + k0);
        bf16x8 b1v = *(const bf16x8*)(pb1 + k0);
        acc00 = __builtin_amdgcn_mfma_f32_16x16x32_bf16(a0, b0,  acc00, 0, 0, 0);
        acc01 = __builtin_amdgcn_mfma_f32_16x16x32_bf16(a0, b1v, acc01, 0, 0, 0);
        acc10 = __builtin_amdgcn_mfma_f32_16x16x32_bf16(a1, b0,  acc10, 0, 0, 0);
        acc11 = __builtin_amdgcn_mfma_f32_16x16x32_bf16(a1, b1v, acc11, 0, 0, 0);
    }

    // C/D layout: col = lane&15, row = (lane>>4)*4 + reg
    const int rbase = g * 4;
#pragma unroll
    for (int r = 0; r < 4; ++r) {
        int row0 = m0 + rbase + r;
        int row1 = row0 + 16;
        int col0 = n0 + lm;
        int col1 = col0 + 16;
        float bb0 = (col0 < PD) ? b1[col0] : 0.0f;
        float bb1 = (col1 < PD) ? b1[col1] : 0.0f;
        C[(size_t)row0 * 1536 + col0] = acc00[r] + bb0;
        C[(size_t)row0 * 1536 + col1] = acc01[r] + bb1;
        C[(size_t)row1 * 1536 + col0] = acc10[r] + bb0;
        C[(size_t)row1 * 1536 + col1] = acc11[r] + bb1;
    }
}

// ---------------------------------------------------------------------------
// Kernel 3: out[b,i,j] = sigmoid( sum_h relu(ha'[i,h]+hb[j,h]) * W2[h] + b2 )
// Grid (jt=4, it=13, b=8) = 416 blocks; block 256.  8 ha rows register-
// resident; each wave streams its j's within a 25-j quarter, pipelined.
// ---------------------------------------------------------------------------
__device__ __forceinline__ float rdot(const float4 A, const float4 C,
                                      const float4 W, float s) {
    s = fmaf(fmaxf(A.x + C.x, 0.f), W.x, s);
    s = fmaf(fmaxf(A.y + C.y, 0.f), W.y, s);
    s = fmaf(fmaxf(A.z + C.z, 0.f), W.z, s);
    s = fmaf(fmaxf(A.w + C.w, 0.f), W.w, s);
    return s;
}

__global__ __launch_bounds__(256) void pair_kernel(
    const float* __restrict__ hab,   // [832,1536]: [:,0:768]=ha+b1, [:,768:]=hb
    const float* __restrict__ W2,    // [768]
    const float* __restrict__ b2,    // [1]
    float* __restrict__ out)         // [8,100,100]
{
    const int jt = blockIdx.x;       // 0..3
    const int i0 = blockIdx.y * 8;   // 0..96
    const int b  = blockIdx.z;       // 0..7
    const int nrows = min(8, PN - i0);
    const int t = threadIdx.x;
    const int wave = t >> 6;
    const int lane = t & 63;

    const float4* w2v = (const float4*)W2;
    const float4 w0 = w2v[lane], w1 = w2v[lane + 64], w2r = w2v[lane + 128];
    const float bb2 = b2[0];

    float4 a[8][3];
#pragma unroll
    for (int i = 0; i < 8; ++i) {
        int row = b * PN + (i < nrows ? i0 + i : i0);
        const float4* ha = (const float4*)(hab + (size_t)row * 1536);
        a[i][0] = ha[lane]; a[i][1] = ha[lane + 64]; a[i][2] = ha[lane + 128];
    }

    const float4* hbbase = (const float4*)(hab + (size_t)(b * PN) * 1536) + 192;
    const int jend = jt * 25 + 25;
    int j = jt * 25 + wave;

    float4 h0, h1, h2;
    {
        const float4* hb = hbbase + (size_t)j * 384;
        h0 = hb[lane]; h1 = hb[lane + 64]; h2 = hb[lane + 128];
    }
    for (; j < jend; j += 4) {
        const float4 c0 = h0, c1 = h1, c2 = h2;
        const int jn = j + 4;
        if (jn < jend) {
            const float4* hb = hbbase + (size_t)jn * 384;
            h0 = hb[lane]; h1 = hb[lane + 64]; h2 = hb[lane + 128];
        }
        float acc[8];
#pragma unroll
        for (int i = 0; i < 8; ++i)
            acc[i] = rdot(a[i][2], c2, w2r,
                     rdot(a[i][1], c1, w1,
                     rdot(a[i][0], c0, w0, 0.f)));
#pragma unroll
        for (int i = 0; i < 8; ++i)
#pragma unroll
            for (int m = 32; m; m >>= 1)
                acc[i] += __shfl_xor(acc[i], m, 64);
        if (lane == 0) {
#pragma unroll
            for (int i = 0; i < 8; ++i)
                if (i < nrows)
                    out[(size_t)(b * PN + i0 + i) * PN + j] =
                        1.0f / (1.0f + expf(-(acc[i] + bb2)));
        }
    }
}

// ---------------------------------------------------------------------------
extern "C" void kernel_launch(void* const* d_in, const int* in_sizes, int n_in,
                              void* d_out, int out_size, void* d_ws, size_t ws_size,
                              hipStream_t stream) {
    const float* patch = (const float*)d_in[0];
    const float* boxes = (const float*)d_in[1];
    const float* W1    = (const float*)d_in[2];
    const float* b1    = (const float*)d_in[3];
    const float* W2    = (const float*)d_in[4];
    const float* b2    = (const float*)d_in[5];
    const int*   img_h = (const int*)d_in[6];
    const int*   img_w = (const int*)d_in[7];
    float* out = (float*)d_out;

    // ws layout (bytes):
    //   pooledh  bf16 [832][768]   = 1,277,952   @ 0
    //   W1T      bf16 [1536][768]  = 2,359,296   @ 1,277,952
    //   hab      f32  [832][1536]  = 5,111,808   @ 3,637,248
    char* wsb = (char*)d_ws;
    __hip_bfloat16* pooledh = (__hip_bfloat16*)(wsb);
    __hip_bfloat16* W1T     = (__hip_bfloat16*)(wsb + 1277952);
    float*          hab     = (float*)(wsb + 3637248);

    pool_prep_kernel<<<MPAD, 256, 0, stream>>>(patch, boxes, W1, img_h, img_w,
                                               pooledh, W1T);
    gemm_mfma_kernel<<<dim3(24, 26), 128, 0, stream>>>(pooledh, W1T, b1, hab);
    pair_kernel<<<dim3(4, 13, 8), 256, 0, stream>>>(hab, W2, b2, out);
}

// Round 7
// 132.267 us; speedup vs baseline: 2.7065x; 1.5624x over previous
//
#include <hip/hip_runtime.h>
#include <hip/hip_bf16.h>
#include <math.h>

// Problem constants: B=8, N=100, D=768, H=768, TH=24, T=577.
#define PB   8
#define PN   100
#define PD   768
#define PT   577
#define PTH  24
#define BN_TOT 800
#define MPAD   832            // 800 padded to 26*32

typedef __attribute__((ext_vector_type(8))) short bf16x8;   // 8 bf16
typedef __attribute__((ext_vector_type(4))) float f32x4;

// ws layout (bytes):
//   Sx       f32 [8][24][25][768]  = 14,745,600   (x-prefix rows, X=0 -> 0)
//   pooledh  bf16 [832][768]       =  1,277,952
//   W1T      bf16 [1536][768]      =  2,359,296
//   hab      f32  [832][1536]      =  5,111,808
#define OFF_POOLED 14745600
#define OFF_W1T    16023552
#define OFF_HAB    18382848

// ---------------------------------------------------------------------------
// Kernel 1 (fused, independent halves):
//   blocks 0..143    : x-prefix of feature map into Sx (float4 over d)
//   blocks 144..1295 : one 32x32 transpose tile each of W1 -> W1T bf16
// ---------------------------------------------------------------------------
#define SATX_BLOCKS 144        // 8*24*192 threads / 256

__global__ __launch_bounds__(256) void prep_kernel(
    const float* __restrict__ patch,   // [8,577,768]
    const float* __restrict__ W1,      // [1536,768]
    float* __restrict__ Sx,
    __hip_bfloat16* __restrict__ W1T)
{
    __shared__ float tile[32][33];
    const int t = threadIdx.x;

    if (blockIdx.x < SATX_BLOCKS) {
        // satx: one thread per (b, y, d4).  Sx[b][y][X][d], X=0..24.
        const int gid = blockIdx.x * 256 + t;       // 0..36863
        const int d4 = gid % 192;
        const int y  = (gid / 192) % PTH;
        const int b  = gid / (192 * PTH);

        const float4* src = (const float4*)(patch +
                            (size_t)(b * PT + 1 + y * PTH) * PD);
        float4* dst = (float4*)(Sx + (size_t)(b * PTH + y) * 25 * PD) + d4;

        dst[0] = make_float4(0.f, 0.f, 0.f, 0.f);
        float4 acc = make_float4(0.f, 0.f, 0.f, 0.f);
#pragma unroll
        for (int X = 1; X <= PTH; ++X) {
            float4 v = src[(size_t)(X - 1) * 192 + d4];
            acc.x += v.x; acc.y += v.y; acc.z += v.z; acc.w += v.w;
            dst[(size_t)X * 192] = acc;
        }
    } else {
        // cvt: W1T[n][k] = W1[k + 768*(n>=768)][n&767]; one tile per block.
        const int tl = blockIdx.x - SATX_BLOCKS;    // 0..1151
        const int hf  = tl / 576;
        const int rem = tl % 576;
        const int k0 = (rem / 24) * 32;
        const int n0 = (rem % 24) * 32;
        const int c  = t & 31;
        const int r4 = t >> 5;                      // 0..7
#pragma unroll
        for (int l = 0; l < 4; ++l) {
            int r = r4 + 8 * l;
            tile[r][c] = W1[(size_t)(hf * PD + k0 + r) * PD + n0 + c];
        }
        __syncthreads();
#pragma unroll
        for (int l = 0; l < 4; ++l) {
            int r = r4 + 8 * l;                     // n-offset within tile
            W1T[(size_t)(hf * PD + n0 + r) * PD + k0 + c] =
                __float2bfloat16(tile[c][r]);
        }
    }
}

// ---------------------------------------------------------------------------
// Kernel 2: pooled row m from x-prefix rows: sum over <=24 y of 2 lookups.
// Block = row m (832 blocks, 192 threads = one float4 d-group each).
// ---------------------------------------------------------------------------
__global__ __launch_bounds__(192) void pool_kernel(
    const float* __restrict__ Sx,
    const float* __restrict__ boxes,   // [800,4]
    const int*   __restrict__ img_h,
    const int*   __restrict__ img_w,
    __hip_bfloat16* __restrict__ pooledh)   // [832,768]
{
    const int m = blockIdx.x;          // 0..831
    const int t = threadIdx.x;         // 0..191
    short4* o = (short4*)(pooledh + (size_t)m * PD) + t;

    if (m >= BN_TOT) {
        short4 z; z.x = 0; z.y = 0; z.z = 0; z.w = 0;
        *o = z;
        return;
    }

    const int b = m / PN;
    const float Wf = (float)img_w[0];
    const float Hf = (float)img_h[0];
    auto to_patch = [](float v, float size) -> int {
        float pix = floorf(v * size);
        float tt  = pix / size * (float)PTH;
        return (int)floorf(tt);
    };
    int px1 = min(max(to_patch(boxes[m * 4 + 0], Wf), 0), PTH - 1);
    int py1 = min(max(to_patch(boxes[m * 4 + 1], Hf), 0), PTH - 1);
    int px2 = min(max(to_patch(boxes[m * 4 + 2], Wf), 1), PTH);
    int py2 = min(max(to_patch(boxes[m * 4 + 3], Hf), 1), PTH);
    if (px2 <= px1) px2 = px1 + 1;
    if (py2 <= py1) py2 = py1 + 1;
    const float inv = 1.0f / (float)((px2 - px1) * (py2 - py1));

    const float4* Sb = (const float4*)(Sx + (size_t)b * PTH * 25 * PD);
    float4 s = make_float4(0.f, 0.f, 0.f, 0.f);
    for (int y = py1; y < py2; ++y) {
        float4 a2 = Sb[(size_t)(y * 25 + px2) * 192 + t];
        float4 a1 = Sb[(size_t)(y * 25 + px1) * 192 + t];
        s.x += a2.x - a1.x; s.y += a2.y - a1.y;
        s.z += a2.z - a1.z; s.w += a2.w - a1.w;
    }
    auto cvt = [](float f) -> short {
        __hip_bfloat16 h = __float2bfloat16(f);
        return *(short*)&h;
    };
    short4 r;
    r.x = cvt(s.x * inv); r.y = cvt(s.y * inv);
    r.z = cvt(s.z * inv); r.w = cvt(s.w * inv);
    *o = r;
}

// ---------------------------------------------------------------------------
// Kernel 3: bf16 MFMA GEMM.  hab[832][1536] = pooledh * W1T^T  (+b1 on n<768).
// Tile 32(M) x 64(N); 2 waves; fragments direct from global (L2-resident).
// ---------------------------------------------------------------------------
__global__ __launch_bounds__(128) void gemm_mfma_kernel(
    const __hip_bfloat16* __restrict__ A,    // pooled bf16 [832][768]
    const __hip_bfloat16* __restrict__ Bt,   // W1T bf16 [1536][768]
    const float* __restrict__ b1,            // [768]
    float* __restrict__ C)                   // hab [832][1536]
{
    const int bn = blockIdx.x;               // 0..23
    const int bm = blockIdx.y;               // 0..25
    const int wave = threadIdx.x >> 6;       // 0..1
    const int lane = threadIdx.x & 63;
    const int lm = lane & 15;
    const int g  = lane >> 4;                // 0..3

    const int m0 = bm * 32;
    const int n0 = bn * 64 + wave * 32;

    const __hip_bfloat16* pa0 = A  + (size_t)(m0 + lm) * PD + g * 8;
    const __hip_bfloat16* pa1 = pa0 + (size_t)16 * PD;
    const __hip_bfloat16* pb0 = Bt + (size_t)(n0 + lm) * PD + g * 8;
    const __hip_bfloat16* pb1 = pb0 + (size_t)16 * PD;

    f32x4 acc00 = {}, acc01 = {}, acc10 = {}, acc11 = {};

#pragma unroll 4
    for (int k0 = 0; k0 < PD; k0 += 32) {
        bf16x8 a0 = *(const bf16x8*)(pa0 + k0);
        bf16x8 a1 = *(const bf16x8*)(pa1 + k0);
        bf16x8 b0 = *(const bf16x8*)(pb0 + k0);
        bf16x8 b1v = *(const bf16x8*)(pb1 + k0);
        acc00 = __builtin_amdgcn_mfma_f32_16x16x32_bf16(a0, b0,  acc00, 0, 0, 0);
        acc01 = __builtin_amdgcn_mfma_f32_16x16x32_bf16(a0, b1v, acc01, 0, 0, 0);
        acc10 = __builtin_amdgcn_mfma_f32_16x16x32_bf16(a1, b0,  acc10, 0, 0, 0);
        acc11 = __builtin_amdgcn_mfma_f32_16x16x32_bf16(a1, b1v, acc11, 0, 0, 0);
    }

    // C/D layout: col = lane&15, row = (lane>>4)*4 + reg
    const int rbase = g * 4;
#pragma unroll
    for (int r = 0; r < 4; ++r) {
        int row0 = m0 + rbase + r;
        int row1 = row0 + 16;
        int col0 = n0 + lm;
        int col1 = col0 + 16;
        float bb0 = (col0 < PD) ? b1[col0] : 0.0f;
        float bb1 = (col1 < PD) ? b1[col1] : 0.0f;
        C[(size_t)row0 * 1536 + col0] = acc00[r] + bb0;
        C[(size_t)row0 * 1536 + col1] = acc01[r] + bb1;
        C[(size_t)row1 * 1536 + col0] = acc10[r] + bb0;
        C[(size_t)row1 * 1536 + col1] = acc11[r] + bb1;
    }
}

// ---------------------------------------------------------------------------
// Kernel 4: out[b,i,j] = sigmoid( sum_h relu(ha'[i,h]+hb[j,h]) * W2[h] + b2 )
// Grid (jt=4, it=13, b=8) = 416 blocks; block 256.  8 ha rows register-
// resident; each wave streams its j's within a 25-j quarter, pipelined.
// ---------------------------------------------------------------------------
__device__ __forceinline__ float rdot(const float4 A, const float4 C,
                                      const float4 W, float s) {
    s = fmaf(fmaxf(A.x + C.x, 0.f), W.x, s);
    s = fmaf(fmaxf(A.y + C.y, 0.f), W.y, s);
    s = fmaf(fmaxf(A.z + C.z, 0.f), W.z, s);
    s = fmaf(fmaxf(A.w + C.w, 0.f), W.w, s);
    return s;
}

__global__ __launch_bounds__(256) void pair_kernel(
    const float* __restrict__ hab,   // [832,1536]: [:,0:768]=ha+b1, [:,768:]=hb
    const float* __restrict__ W2,    // [768]
    const float* __restrict__ b2,    // [1]
    float* __restrict__ out)         // [8,100,100]
{
    const int jt = blockIdx.x;       // 0..3
    const int i0 = blockIdx.y * 8;   // 0..96
    const int b  = blockIdx.z;       // 0..7
    const int nrows = min(8, PN - i0);
    const int t = threadIdx.x;
    const int wave = t >> 6;
    const int lane = t & 63;

    const float4* w2v = (const float4*)W2;
    const float4 w0 = w2v[lane], w1 = w2v[lane + 64], w2r = w2v[lane + 128];
    const float bb2 = b2[0];

    float4 a[8][3];
#pragma unroll
    for (int i = 0; i < 8; ++i) {
        int row = b * PN + (i < nrows ? i0 + i : i0);
        const float4* ha = (const float4*)(hab + (size_t)row * 1536);
        a[i][0] = ha[lane]; a[i][1] = ha[lane + 64]; a[i][2] = ha[lane + 128];
    }

    const float4* hbbase = (const float4*)(hab + (size_t)(b * PN) * 1536) + 192;
    const int jend = jt * 25 + 25;
    int j = jt * 25 + wave;

    float4 h0, h1, h2;
    {
        const float4* hb = hbbase + (size_t)j * 384;
        h0 = hb[lane]; h1 = hb[lane + 64]; h2 = hb[lane + 128];
    }
    for (; j < jend; j += 4) {
        const float4 c0 = h0, c1 = h1, c2 = h2;
        const int jn = j + 4;
        if (jn < jend) {
            const float4* hb = hbbase + (size_t)jn * 384;
            h0 = hb[lane]; h1 = hb[lane + 64]; h2 = hb[lane + 128];
        }
        float acc[8];
#pragma unroll
        for (int i = 0; i < 8; ++i)
            acc[i] = rdot(a[i][2], c2, w2r,
                     rdot(a[i][1], c1, w1,
                     rdot(a[i][0], c0, w0, 0.f)));
#pragma unroll
        for (int i = 0; i < 8; ++i)
#pragma unroll
            for (int m = 32; m; m >>= 1)
                acc[i] += __shfl_xor(acc[i], m, 64);
        if (lane == 0) {
#pragma unroll
            for (int i = 0; i < 8; ++i)
                if (i < nrows)
                    out[(size_t)(b * PN + i0 + i) * PN + j] =
                        1.0f / (1.0f + expf(-(acc[i] + bb2)));
        }
    }
}

// ---------------------------------------------------------------------------
extern "C" void kernel_launch(void* const* d_in, const int* in_sizes, int n_in,
                              void* d_out, int out_size, void* d_ws, size_t ws_size,
                              hipStream_t stream) {
    const float* patch = (const float*)d_in[0];
    const float* boxes = (const float*)d_in[1];
    const float* W1    = (const float*)d_in[2];
    const float* b1    = (const float*)d_in[3];
    const float* W2    = (const float*)d_in[4];
    const float* b2    = (const float*)d_in[5];
    const int*   img_h = (const int*)d_in[6];
    const int*   img_w = (const int*)d_in[7];
    float* out = (float*)d_out;

    char* wsb = (char*)d_ws;
    float*          Sx      = (float*)(wsb);
    __hip_bfloat16* pooledh = (__hip_bfloat16*)(wsb + OFF_POOLED);
    __hip_bfloat16* W1T     = (__hip_bfloat16*)(wsb + OFF_W1T);
    float*          hab     = (float*)(wsb + OFF_HAB);

    prep_kernel<<<SATX_BLOCKS + 1152, 256, 0, stream>>>(patch, W1, Sx, W1T);
    pool_kernel<<<MPAD, 192, 0, stream>>>(Sx, boxes, img_h, img_w, pooledh);
    gemm_mfma_kernel<<<dim3(24, 26), 128, 0, stream>>>(pooledh, W1T, b1, hab);
    pair_kernel<<<dim3(4, 13, 8), 256, 0, stream>>>(hab, W2, b2, out);
}